// Round 7
// baseline (360.029 us; speedup 1.0000x reference)
//
#include <hip/hip_runtime.h>

#define BB 8
#define NN 8192
#define SS 2048
#define CC 64
#define NS 32
#define COUT 67        // 3 xyz + 64 feature channels
#define QT 4           // queries per block (one scan-wave each)
#define SLOTS (QT*NS)  // 128 (query,sample) slots per block
#define HSTR 33        // half-tile LDS stride: write free, transpose-read 2-way
#define REP 3          // DIAGNOSTIC: repeat whole kernel to exceed the top-5
                       // cutoff (~85us fills) and expose our counters.
                       // Idempotent: same idx -> same output values each rep.

// ---------------- Fused kernel: scan (wave-per-query) + gather --------------
// R5-best structure (dbuf reverted), wrapped in REP=3 for counter visibility.
__global__ __launch_bounds__(256, 6) void fused_rep3_diag(
    const float* __restrict__ xyz,      // (B, N, 3)
    const float* __restrict__ new_xyz,  // (B, S, 3)
    const float* __restrict__ feat,     // (B, N, C)
    float* __restrict__ out)            // (B, 67, S, NS)
{
#pragma clang fp contract(off)
    __shared__ float fh[SLOTS * HSTR];   // 128*33*4B = 16.5 KB (half channels)
    __shared__ float xt[3 * SLOTS];      // 1.5 KB, [plane][slot]
    __shared__ int idx_sh[SLOTS];        // 0.5 KB

    const int t   = threadIdx.x;
    const int w   = t >> 6;              // wave 0..3
    const int ln  = t & 63;
    const int bid = blockIdx.x;          // 0..4095, b-fastest (XCD-affine)
    const int b     = bid & 7;
    const int sTile = bid >> 3;          // 0..511
    const int s0 = sTile * QT;

    for (int rep = 0; rep < REP; ++rep) {
    // ================= Phase 1: ball-query scan (bit-exact) =================
    {
        const int s = s0 + w;
        const float R2 = 0.04f;          // strict '<' matches ref

        const float* ctr = new_xyz + ((size_t)b * SS + s) * 3;
        const float cx = ctr[0], cy = ctr[1], cz = ctr[2];
        const float* xb = xyz + (size_t)b * NN * 3;

        int* myidx = idx_sh + (w << 5);
        const unsigned long long lt = (1ull << ln) - 1ull;

        int total = 0;
        int firstIdx = -1;
        for (int j0 = 0; j0 < NN && total < NS; j0 += 256) {
            // 48B-aligned: (j0 + 4*ln)*12 bytes is a multiple of 48
            const float4* p4 = (const float4*)(xb + (size_t)(j0 + (ln << 2)) * 3);
            const float4 A  = p4[0];   // x0 y0 z0 x1
            const float4 Bv = p4[1];   // y1 z1 x2 y2
            const float4 Cv = p4[2];   // z2 x3 y3 z3
            float d2v[4];
            {
                const float dx = A.x - cx, dy = A.y - cy, dz = A.z - cz;
                float d2 = dx * dx; d2 = d2 + dy * dy; d2 = d2 + dz * dz;
                d2v[0] = d2;
            }
            {
                const float dx = A.w - cx, dy = Bv.x - cy, dz = Bv.y - cz;
                float d2 = dx * dx; d2 = d2 + dy * dy; d2 = d2 + dz * dz;
                d2v[1] = d2;
            }
            {
                const float dx = Bv.z - cx, dy = Bv.w - cy, dz = Cv.x - cz;
                float d2 = dx * dx; d2 = d2 + dy * dy; d2 = d2 + dz * dz;
                d2v[2] = d2;
            }
            {
                const float dx = Cv.y - cx, dy = Cv.z - cy, dz = Cv.w - cz;
                float d2 = dx * dx; d2 = d2 + dy * dy; d2 = d2 + dz * dz;
                d2v[3] = d2;
            }

            unsigned long long M[4];
#pragma unroll
            for (int u = 0; u < 4; ++u) M[u] = __ballot(d2v[u] < R2);

            if (firstIdx < 0) {
                int fmin = 0x7fffffff;
#pragma unroll
                for (int u = 0; u < 4; ++u)
                    if (M[u] != 0ull) {
                        const int j = j0 + (__builtin_ctzll(M[u]) << 2) + u;
                        fmin = (j < fmin) ? j : fmin;
                    }
                if (fmin != 0x7fffffff) firstIdx = fmin;
            }

            int below = 0;   // hits in earlier lanes (any u) -> smaller j
#pragma unroll
            for (int u = 0; u < 4; ++u) below += (int)__popcll(M[u] & lt);

            int own = 0;     // own hits with smaller u -> smaller j
#pragma unroll
            for (int u = 0; u < 4; ++u) {
                if (d2v[u] < R2) {
                    const int pos = total + below + own;
                    if (pos < NS) myidx[pos] = j0 + (ln << 2) + u;
                    ++own;
                }
            }
#pragma unroll
            for (int u = 0; u < 4; ++u) total += (int)__popcll(M[u]);
        }
        if (total < NS) {
            const int fill = (total > 0) ? firstIdx : 0;
            if (ln >= total && ln < NS) myidx[ln] = fill;
        }
    }
    __syncthreads();

    // ================= Phase 2: gather, half-channel staged =================
    // ---- xyz planes: one slot per thread (small, divergent but tiny) ----
    if (t < SLOTS) {
        const int r = idx_sh[t];
        const int q = t >> 5;
        const float* ctr = new_xyz + ((size_t)b * SS + s0 + q) * 3;
        const float* p   = xyz + ((size_t)b * NN + r) * 3;
        xt[0 * SLOTS + t] = p[0] - ctr[0];
        xt[1 * SLOTS + t] = p[1] - ctr[1];
        xt[2 * SLOTS + t] = p[2] - ctr[2];
    }

    const int c32 = ln & 31;             // channel within half
    const int sub = ln >> 5;             // which of 2 rows this lane covers
    const float* fb = feat + (size_t)b * NN * CC;
    const size_t plane = (size_t)SS * NS;
    float* ob = out + ((size_t)b * COUT * SS + s0) * NS;

    // ---- stage half 0: channels 0..31 for all 128 slots ----
    for (int i = 0; i < 16; i += 4) {
        float v[4];
        int   mm[4];
#pragma unroll
        for (int u = 0; u < 4; ++u) {
            const int m = (w << 5) + ((i + u) << 1) + sub;
            mm[u] = m;
            v[u]  = fb[(size_t)idx_sh[m] * CC + c32];
        }
#pragma unroll
        for (int u = 0; u < 4; ++u)
            fh[mm[u] * HSTR + c32] = v[u];             // 2 lanes/bank, free
    }
    __syncthreads();

    // ---- write-out planes 0..34: 70 tasks of one 256B wave-store ----
    for (int i = 0; i < 18; ++i) {
        const int tau = (i << 2) + w;
        if (tau < 70) {
            const int p  = tau >> 1;
            const int sl = ((tau & 1) << 6) + ln;
            const float val = (p < 3) ? xt[p * SLOTS + sl]
                                      : fh[sl * HSTR + (p - 3)];  // 2-way, free
            ob[(size_t)p * plane + sl] = val;
        }
    }
    __syncthreads();

    // ---- stage half 1: channels 32..63 ----
    for (int i = 0; i < 16; i += 4) {
        float v[4];
        int   mm[4];
#pragma unroll
        for (int u = 0; u < 4; ++u) {
            const int m = (w << 5) + ((i + u) << 1) + sub;
            mm[u] = m;
            v[u]  = fb[(size_t)idx_sh[m] * CC + 32 + c32];
        }
#pragma unroll
        for (int u = 0; u < 4; ++u)
            fh[mm[u] * HSTR + c32] = v[u];
    }
    __syncthreads();

    // ---- write-out planes 35..66: exactly 64 tasks ----
    for (int i = 0; i < 16; ++i) {
        const int tau = (i << 2) + w;
        const int pl  = tau >> 1;                       // 0..31
        const int sl  = ((tau & 1) << 6) + ln;
        ob[(size_t)(35 + pl) * plane + sl] = fh[sl * HSTR + pl];
    }
    __syncthreads();   // rep boundary: fh reads done before next rep stages
    }  // rep
}

extern "C" void kernel_launch(void* const* d_in, const int* in_sizes, int n_in,
                              void* d_out, int out_size, void* d_ws, size_t ws_size,
                              hipStream_t stream) {
    const float* xyz     = (const float*)d_in[0];
    const float* new_xyz = (const float*)d_in[1];
    const float* feat    = (const float*)d_in[2];
    float* out = (float*)d_out;
    (void)d_ws; (void)ws_size;   // idx lives in LDS

    fused_rep3_diag<<<dim3((BB * SS) / QT), dim3(256), 0, stream>>>(xyz, new_xyz, feat, out);
}

// Round 8
// 183.585 us; speedup vs baseline: 1.9611x; 1.9611x over previous
//
#include <hip/hip_runtime.h>

#define BB 8
#define NN 8192
#define SS 2048
#define CC 64
#define NS 32
#define COUT 67        // 3 xyz + 64 feature channels
#define QT 4           // queries per block (one scan-wave each)
#define SLOTS (QT*NS)  // 128 (query,sample) slots per block
#define HSTR 33        // half-tile LDS stride: write free, transpose-read 2-way

// ---------------- Fused kernel: scan (wave-per-query) + gather --------------
// R5-best structure + NONTEMPORAL output stores. R7's REP=3 counters showed
// 220 MB/rep HBM writes (1.6x the 137 MB output) and 103 MB/rep fetch
// (~5x compulsory): write-allocate RFO pulls every output line through L2
// before overwriting it, then amplifies the writeback. Output is write-once,
// never re-read -> bypass L2 entirely with nt stores.
__global__ __launch_bounds__(256, 6) void fused_kernel(
    const float* __restrict__ xyz,      // (B, N, 3)
    const float* __restrict__ new_xyz,  // (B, S, 3)
    const float* __restrict__ feat,     // (B, N, C)
    float* __restrict__ out)            // (B, 67, S, NS)
{
#pragma clang fp contract(off)
    __shared__ float fh[SLOTS * HSTR];   // 128*33*4B = 16.5 KB (half channels)
    __shared__ float xt[3 * SLOTS];      // 1.5 KB, [plane][slot]
    __shared__ int idx_sh[SLOTS];        // 0.5 KB

    const int t   = threadIdx.x;
    const int w   = t >> 6;              // wave 0..3
    const int ln  = t & 63;
    const int bid = blockIdx.x;          // 0..4095, b-fastest (XCD-affine)
    const int b     = bid & 7;
    const int sTile = bid >> 3;          // 0..511
    const int s0 = sTile * QT;

    // ================= Phase 1: ball-query scan (bit-exact) =================
    {
        const int s = s0 + w;
        const float R2 = 0.04f;          // strict '<' matches ref

        const float* ctr = new_xyz + ((size_t)b * SS + s) * 3;
        const float cx = ctr[0], cy = ctr[1], cz = ctr[2];
        const float* xb = xyz + (size_t)b * NN * 3;

        int* myidx = idx_sh + (w << 5);
        const unsigned long long lt = (1ull << ln) - 1ull;

        int total = 0;
        int firstIdx = -1;
        for (int j0 = 0; j0 < NN && total < NS; j0 += 256) {
            // 48B-aligned: (j0 + 4*ln)*12 bytes is a multiple of 48
            const float4* p4 = (const float4*)(xb + (size_t)(j0 + (ln << 2)) * 3);
            const float4 A  = p4[0];   // x0 y0 z0 x1
            const float4 Bv = p4[1];   // y1 z1 x2 y2
            const float4 Cv = p4[2];   // z2 x3 y3 z3
            float d2v[4];
            {
                const float dx = A.x - cx, dy = A.y - cy, dz = A.z - cz;
                float d2 = dx * dx; d2 = d2 + dy * dy; d2 = d2 + dz * dz;
                d2v[0] = d2;
            }
            {
                const float dx = A.w - cx, dy = Bv.x - cy, dz = Bv.y - cz;
                float d2 = dx * dx; d2 = d2 + dy * dy; d2 = d2 + dz * dz;
                d2v[1] = d2;
            }
            {
                const float dx = Bv.z - cx, dy = Bv.w - cy, dz = Cv.x - cz;
                float d2 = dx * dx; d2 = d2 + dy * dy; d2 = d2 + dz * dz;
                d2v[2] = d2;
            }
            {
                const float dx = Cv.y - cx, dy = Cv.z - cy, dz = Cv.w - cz;
                float d2 = dx * dx; d2 = d2 + dy * dy; d2 = d2 + dz * dz;
                d2v[3] = d2;
            }

            unsigned long long M[4];
#pragma unroll
            for (int u = 0; u < 4; ++u) M[u] = __ballot(d2v[u] < R2);

            if (firstIdx < 0) {
                int fmin = 0x7fffffff;
#pragma unroll
                for (int u = 0; u < 4; ++u)
                    if (M[u] != 0ull) {
                        const int j = j0 + (__builtin_ctzll(M[u]) << 2) + u;
                        fmin = (j < fmin) ? j : fmin;
                    }
                if (fmin != 0x7fffffff) firstIdx = fmin;
            }

            int below = 0;   // hits in earlier lanes (any u) -> smaller j
#pragma unroll
            for (int u = 0; u < 4; ++u) below += (int)__popcll(M[u] & lt);

            int own = 0;     // own hits with smaller u -> smaller j
#pragma unroll
            for (int u = 0; u < 4; ++u) {
                if (d2v[u] < R2) {
                    const int pos = total + below + own;
                    if (pos < NS) myidx[pos] = j0 + (ln << 2) + u;
                    ++own;
                }
            }
#pragma unroll
            for (int u = 0; u < 4; ++u) total += (int)__popcll(M[u]);
        }
        if (total < NS) {
            const int fill = (total > 0) ? firstIdx : 0;
            if (ln >= total && ln < NS) myidx[ln] = fill;
        }
    }
    __syncthreads();

    // ================= Phase 2: gather, half-channel staged =================
    // ---- xyz planes: one slot per thread (small, divergent but tiny) ----
    if (t < SLOTS) {
        const int r = idx_sh[t];
        const int q = t >> 5;
        const float* ctr = new_xyz + ((size_t)b * SS + s0 + q) * 3;
        const float* p   = xyz + ((size_t)b * NN + r) * 3;
        xt[0 * SLOTS + t] = p[0] - ctr[0];
        xt[1 * SLOTS + t] = p[1] - ctr[1];
        xt[2 * SLOTS + t] = p[2] - ctr[2];
    }

    const int c32 = ln & 31;             // channel within half
    const int sub = ln >> 5;             // which of 2 rows this lane covers
    const float* fb = feat + (size_t)b * NN * CC;
    const size_t plane = (size_t)SS * NS;
    float* ob = out + ((size_t)b * COUT * SS + s0) * NS;

    // ---- stage half 0: channels 0..31 for all 128 slots ----
    for (int i = 0; i < 16; i += 4) {
        float v[4];
        int   mm[4];
#pragma unroll
        for (int u = 0; u < 4; ++u) {
            const int m = (w << 5) + ((i + u) << 1) + sub;
            mm[u] = m;
            v[u]  = fb[(size_t)idx_sh[m] * CC + c32];
        }
#pragma unroll
        for (int u = 0; u < 4; ++u)
            fh[mm[u] * HSTR + c32] = v[u];             // 2 lanes/bank, free
    }
    __syncthreads();

    // ---- write-out planes 0..34: 70 tasks of one 256B nt wave-store ----
    for (int i = 0; i < 18; ++i) {
        const int tau = (i << 2) + w;
        if (tau < 70) {
            const int p  = tau >> 1;
            const int sl = ((tau & 1) << 6) + ln;
            const float val = (p < 3) ? xt[p * SLOTS + sl]
                                      : fh[sl * HSTR + (p - 3)];  // 2-way, free
            __builtin_nontemporal_store(val, ob + (size_t)p * plane + sl);
        }
    }
    __syncthreads();

    // ---- stage half 1: channels 32..63 ----
    for (int i = 0; i < 16; i += 4) {
        float v[4];
        int   mm[4];
#pragma unroll
        for (int u = 0; u < 4; ++u) {
            const int m = (w << 5) + ((i + u) << 1) + sub;
            mm[u] = m;
            v[u]  = fb[(size_t)idx_sh[m] * CC + 32 + c32];
        }
#pragma unroll
        for (int u = 0; u < 4; ++u)
            fh[mm[u] * HSTR + c32] = v[u];
    }
    __syncthreads();

    // ---- write-out planes 35..66: exactly 64 tasks ----
    for (int i = 0; i < 16; ++i) {
        const int tau = (i << 2) + w;
        const int pl  = tau >> 1;                       // 0..31
        const int sl  = ((tau & 1) << 6) + ln;
        __builtin_nontemporal_store(fh[sl * HSTR + pl],
                                    ob + (size_t)(35 + pl) * plane + sl);
    }
}

extern "C" void kernel_launch(void* const* d_in, const int* in_sizes, int n_in,
                              void* d_out, int out_size, void* d_ws, size_t ws_size,
                              hipStream_t stream) {
    const float* xyz     = (const float*)d_in[0];
    const float* new_xyz = (const float*)d_in[1];
    const float* feat    = (const float*)d_in[2];
    float* out = (float*)d_out;
    (void)d_ws; (void)ws_size;   // idx lives in LDS

    fused_kernel<<<dim3((BB * SS) / QT), dim3(256), 0, stream>>>(xyz, new_xyz, feat, out);
}

// Round 9
// 175.518 us; speedup vs baseline: 2.0512x; 1.0460x over previous
//
#include <hip/hip_runtime.h>

#define BB 8
#define NN 8192
#define SS 2048
#define CC 64
#define NS 32
#define COUT 67        // 3 xyz + 64 feature channels
#define QT 8           // queries per block (each wave scans 2)
#define SLOTS (QT*NS)  // 256 (query,sample) slots per block
#define SP 260         // padded c-major LDS stride (floats): 2-way banks, free

// ---------------- Fused kernel: scan + gather, 1KB plane runs ---------------
// R7 counters: 220MB/rep writes (1.6x compulsory), 103MB/rep fetch (~5x),
// 4 TB/s, VALU 21% -> memory-bound with amplification. R8: NT stores hurt
// (twice-replicated) -> the L2 path is needed; the amplification lever is
// RUN GRANULARITY. This version: 256 slots/block, quarter-channel c-major
// staging -> each output plane run is 1KB, stored by ONE wave float4 instr.
// Feat reads are per-lane float4 (16 slots/wave-instr). Scan bit-exact.
__global__ __launch_bounds__(256, 6) void fused_kernel(
    const float* __restrict__ xyz,      // (B, N, 3)
    const float* __restrict__ new_xyz,  // (B, S, 3)
    const float* __restrict__ feat,     // (B, N, C)
    float* __restrict__ out)            // (B, 67, S, NS)
{
#pragma clang fp contract(off)
    __shared__ float fh[16 * SP];        // 16.6 KB: 16 channels x 256 slots
    __shared__ float xt[3 * SP];         // 3.1 KB:  3 xyz planes x 256 slots
    __shared__ int idx_sh[SLOTS];        // 1 KB

    const int t   = threadIdx.x;
    const int w   = t >> 6;              // wave 0..3
    const int ln  = t & 63;
    const int bid = blockIdx.x;          // 0..2047, b-fastest (XCD-affine)
    const int b     = bid & 7;
    const int sTile = bid >> 3;          // 0..255
    const int s0 = sTile * QT;

    // ================= Phase 1: ball-query scan (bit-exact) =================
    // Wave w scans queries q = w and q = w+4 with the verified R5 loop.
    for (int qi = 0; qi < 2; ++qi) {
        const int q = (qi << 2) + w;
        const int s = s0 + q;
        const float R2 = 0.04f;          // strict '<' matches ref

        const float* ctr = new_xyz + ((size_t)b * SS + s) * 3;
        const float cx = ctr[0], cy = ctr[1], cz = ctr[2];
        const float* xb = xyz + (size_t)b * NN * 3;

        int* myidx = idx_sh + (q << 5);
        const unsigned long long lt = (1ull << ln) - 1ull;

        int total = 0;
        int firstIdx = -1;
        for (int j0 = 0; j0 < NN && total < NS; j0 += 256) {
            // 48B-aligned: (j0 + 4*ln)*12 bytes is a multiple of 48
            const float4* p4 = (const float4*)(xb + (size_t)(j0 + (ln << 2)) * 3);
            const float4 A  = p4[0];   // x0 y0 z0 x1
            const float4 Bv = p4[1];   // y1 z1 x2 y2
            const float4 Cv = p4[2];   // z2 x3 y3 z3
            float d2v[4];
            {
                const float dx = A.x - cx, dy = A.y - cy, dz = A.z - cz;
                float d2 = dx * dx; d2 = d2 + dy * dy; d2 = d2 + dz * dz;
                d2v[0] = d2;
            }
            {
                const float dx = A.w - cx, dy = Bv.x - cy, dz = Bv.y - cz;
                float d2 = dx * dx; d2 = d2 + dy * dy; d2 = d2 + dz * dz;
                d2v[1] = d2;
            }
            {
                const float dx = Bv.z - cx, dy = Bv.w - cy, dz = Cv.x - cz;
                float d2 = dx * dx; d2 = d2 + dy * dy; d2 = d2 + dz * dz;
                d2v[2] = d2;
            }
            {
                const float dx = Cv.y - cx, dy = Cv.z - cy, dz = Cv.w - cz;
                float d2 = dx * dx; d2 = d2 + dy * dy; d2 = d2 + dz * dz;
                d2v[3] = d2;
            }

            unsigned long long M[4];
#pragma unroll
            for (int u = 0; u < 4; ++u) M[u] = __ballot(d2v[u] < R2);

            if (firstIdx < 0) {
                int fmin = 0x7fffffff;
#pragma unroll
                for (int u = 0; u < 4; ++u)
                    if (M[u] != 0ull) {
                        const int j = j0 + (__builtin_ctzll(M[u]) << 2) + u;
                        fmin = (j < fmin) ? j : fmin;
                    }
                if (fmin != 0x7fffffff) firstIdx = fmin;
            }

            int below = 0;   // hits in earlier lanes (any u) -> smaller j
#pragma unroll
            for (int u = 0; u < 4; ++u) below += (int)__popcll(M[u] & lt);

            int own = 0;     // own hits with smaller u -> smaller j
#pragma unroll
            for (int u = 0; u < 4; ++u) {
                if (d2v[u] < R2) {
                    const int pos = total + below + own;
                    if (pos < NS) myidx[pos] = j0 + (ln << 2) + u;
                    ++own;
                }
            }
#pragma unroll
            for (int u = 0; u < 4; ++u) total += (int)__popcll(M[u]);
        }
        if (total < NS) {
            const int fill = (total > 0) ? firstIdx : 0;
            if (ln >= total && ln < NS) myidx[ln] = fill;
        }
    }
    __syncthreads();

    // ================= Phase 2: gather, quarter-channel staged ==============
    const int c4  = ln & 3;              // float4 index within 16-ch stage
    const int ms  = ln >> 2;             // 16 slots per wave-instr
    const float* fb = feat + (size_t)b * NN * CC;
    const size_t plane = (size_t)SS * NS;
    float* ob = out + ((size_t)b * COUT * SS + s0) * NS;

    // ---- xyz planes: one slot per thread, c-major xt[p][slot] ----
    {
        const int r = idx_sh[t];
        const int q = t >> 5;
        const float* ctr = new_xyz + ((size_t)b * SS + s0 + q) * 3;
        const float* p   = xyz + ((size_t)b * NN + r) * 3;
        xt[0 * SP + t] = p[0] - ctr[0];
        xt[1 * SP + t] = p[1] - ctr[1];
        xt[2 * SP + t] = p[2] - ctr[2];
    }

#pragma unroll
    for (int st = 0; st < 4; ++st) {
        if (st > 0) __syncthreads();     // prev write-out done reading fh

        // ---- stage st: channels 16st..16st+15 for all 256 slots ----
        // wave w covers slots 64w..64w+63; 16 slots per float4 wave-load.
        float4 vv[4];
        int    mm[4];
#pragma unroll
        for (int i = 0; i < 4; ++i) {
            mm[i] = (w << 6) + (i << 4) + ms;
            vv[i] = *(const float4*)(fb + (size_t)idx_sh[mm[i]] * CC
                                     + (st << 4) + (c4 << 2));
        }
#pragma unroll
        for (int i = 0; i < 4; ++i) {
            fh[((c4 << 2) + 0) * SP + mm[i]] = vv[i].x;   // 2-way banks, free
            fh[((c4 << 2) + 1) * SP + mm[i]] = vv[i].y;
            fh[((c4 << 2) + 2) * SP + mm[i]] = vv[i].z;
            fh[((c4 << 2) + 3) * SP + mm[i]] = vv[i].w;
        }
        __syncthreads();

        // ---- write-out: one 1KB full-wave float4 store per plane ----
        if (st == 0) {
            // planes 0..18: 3 xyz + ch 0..15
            for (int i = 0; i < 5; ++i) {
                const int tau = (i << 2) + w;
                if (tau < 19) {
                    const float* src = (tau < 3) ? (xt + tau * SP)
                                                 : (fh + (tau - 3) * SP);
                    const float4 v = *(const float4*)(src + (ln << 2));
                    *(float4*)(ob + (size_t)tau * plane + (ln << 2)) = v;
                }
            }
        } else {
            // planes 3+16st .. 3+16st+15
#pragma unroll
            for (int i = 0; i < 4; ++i) {
                const int tau = (i << 2) + w;
                const float4 v = *(const float4*)(fh + tau * SP + (ln << 2));
                *(float4*)(ob + (size_t)(3 + (st << 4) + tau) * plane
                           + (ln << 2)) = v;
            }
        }
    }
}

extern "C" void kernel_launch(void* const* d_in, const int* in_sizes, int n_in,
                              void* d_out, int out_size, void* d_ws, size_t ws_size,
                              hipStream_t stream) {
    const float* xyz     = (const float*)d_in[0];
    const float* new_xyz = (const float*)d_in[1];
    const float* feat    = (const float*)d_in[2];
    float* out = (float*)d_out;
    (void)d_ws; (void)ws_size;   // idx lives in LDS

    fused_kernel<<<dim3((BB * SS) / QT), dim3(256), 0, stream>>>(xyz, new_xyz, feat, out);
}